// Round 3
// baseline (2128.926 us; speedup 1.0000x reference)
//
#include <hip/hip_runtime.h>
#include <hip/hip_fp16.h>

// GNN NodeModel on MI355X — round 3 restructure.
// Edge: GEMM1(K=96, bf16 MFMA) -> BN -> ReLU -> packed-f16 atomic scatter of r.
// Node: agg=(rsum/cnt)@W2+b2 -> GEMM3 -> BN -> ReLU -> GEMM4 -> out.
// No LDS / no __syncthreads in edge kernels: 16-edge tile per WAVE, B-matrix in
// registers, A-fragments loaded straight from global (coalesced per 16-lane group).
// Column mapping n = 4*(lane&15) + j => each lane owns 4 consecutive columns
// (enables pk_add_f16x2 atomics and float4 stores).
// b1/b3 skipped: BN mean-subtraction cancels them exactly.

#define HID 64
#define RPAD 72
#define BN_EPS 1e-5f

typedef __attribute__((ext_vector_type(8))) short bf16x8;
typedef __attribute__((ext_vector_type(4))) short bf16x4;
typedef __attribute__((ext_vector_type(4))) float f32x4;

static __device__ __forceinline__ short f2bf(float f) {
  union { float fv; unsigned u; } v; v.fv = f;
  unsigned r = v.u + 0x7FFFu + ((v.u >> 16) & 1u);  // round-to-nearest-even
  return (short)(r >> 16);
}

#define Z8 {0,0,0,0,0,0,0,0}

// B-frags for K=96 concat([x(3) , feat(64)]) weight w[67][64]:
// frag[ks][j] element jj corresponds to k=ks*32+kg*8+jj, col n=4*l15+j.
// A-layout cols 0..63 = feat -> w row 3+k ; cols 64..66 = x -> w row k-64.
static __device__ __forceinline__ void load_B96(bf16x8 Bf[3][4], const float* __restrict__ w,
                                                int l15, int kg) {
  #pragma unroll
  for (int ks = 0; ks < 3; ++ks)
    #pragma unroll
    for (int j = 0; j < 4; ++j) {
      bf16x8 b = Z8;
      #pragma unroll
      for (int jj = 0; jj < 8; ++jj) {
        int k = ks * 32 + kg * 8 + jj;
        int n = 4 * l15 + j;
        float v = 0.f;
        if (k < 64)      v = w[(size_t)(3 + k) * HID + n];
        else if (k < 67) v = w[(size_t)(k - 64) * HID + n];
        b[jj] = f2bf(v);
      }
      Bf[ks][j] = b;
    }
}

// B-frags for K=64 weight w[64][64] (w2 / w4).
static __device__ __forceinline__ void load_B64(bf16x8 Bf[2][4], const float* __restrict__ w,
                                                int l15, int kg) {
  #pragma unroll
  for (int ks = 0; ks < 2; ++ks)
    #pragma unroll
    for (int j = 0; j < 4; ++j) {
      bf16x8 b = Z8;
      #pragma unroll
      for (int jj = 0; jj < 8; ++jj) {
        int k = ks * 32 + kg * 8 + jj;
        int n = 4 * l15 + j;
        b[jj] = f2bf(w[(size_t)k * HID + n]);
      }
      Bf[ks][j] = b;
    }
}

// Edge A-frags: lane covers row e0+l15, k-chunk kg*8 within each ks block.
static __device__ __forceinline__ void edge_A(bf16x8 A[3], const float* __restrict__ attr,
                                              const int* __restrict__ ei_row,
                                              const float* __restrict__ x,
                                              long e0, int E, int l15, int kg) {
  bf16x8 a0 = Z8, a1 = Z8, a2 = Z8;
  long e = e0 + l15;
  if (e < E) {
    const float* ar = attr + (size_t)e * HID + kg * 8;
    f32x4 p0 = *(const f32x4*)(ar);
    f32x4 p1 = *(const f32x4*)(ar + 4);
    f32x4 p2 = *(const f32x4*)(ar + 32);
    f32x4 p3 = *(const f32x4*)(ar + 36);
    #pragma unroll
    for (int t = 0; t < 4; ++t) {
      a0[t] = f2bf(p0[t]); a0[4 + t] = f2bf(p1[t]);
      a1[t] = f2bf(p2[t]); a1[4 + t] = f2bf(p3[t]);
    }
    if (kg == 0) {
      int nd = ei_row[e];
      a2[0] = f2bf(x[(size_t)nd * 3]);
      a2[1] = f2bf(x[(size_t)nd * 3 + 1]);
      a2[2] = f2bf(x[(size_t)nd * 3 + 2]);
    }
  }
  A[0] = a0; A[1] = a1; A[2] = a2;
}

// Node A-frags: cols 0..63 = agg (already bf16), 64..66 = x[n].
static __device__ __forceinline__ void node_A(bf16x8 A[3], const short* __restrict__ aggb,
                                              const float* __restrict__ x,
                                              long n0, int N, int l15, int kg) {
  bf16x8 a0 = Z8, a1 = Z8, a2 = Z8;
  long n = n0 + l15;
  if (n < N) {
    a0 = *(const bf16x8*)(aggb + (size_t)n * HID + kg * 8);
    a1 = *(const bf16x8*)(aggb + (size_t)n * HID + 32 + kg * 8);
    if (kg == 0) {
      a2[0] = f2bf(x[(size_t)n * 3]);
      a2[1] = f2bf(x[(size_t)n * 3 + 1]);
      a2[2] = f2bf(x[(size_t)n * 3 + 2]);
    }
  }
  A[0] = a0; A[1] = a1; A[2] = a2;
}

__global__ __launch_bounds__(256) void k_edge_stats(
    const float* __restrict__ attr, const int* __restrict__ ei_row,
    const float* __restrict__ x, const float* __restrict__ w1,
    float* __restrict__ gsum, float* __restrict__ gsq, int E, int numTiles) {
  const int tid = threadIdx.x;
  const int wv = tid >> 6, lane = tid & 63;
  const int l15 = lane & 15, kg = lane >> 4;
  bf16x8 B[3][4];
  load_B96(B, w1, l15, kg);

  float rs[4] = {0.f, 0.f, 0.f, 0.f};
  float rq[4] = {0.f, 0.f, 0.f, 0.f};
  const f32x4 z = {0.f, 0.f, 0.f, 0.f};
  const int wstride = gridDim.x * 4;

  for (int t = blockIdx.x * 4 + wv; t < numTiles; t += wstride) {
    bf16x8 A[3];
    edge_A(A, attr, ei_row, x, (long)t * 16, E, l15, kg);
    f32x4 acc[4]; acc[0] = z; acc[1] = z; acc[2] = z; acc[3] = z;
    #pragma unroll
    for (int ks = 0; ks < 3; ++ks)
      #pragma unroll
      for (int j = 0; j < 4; ++j)
        acc[j] = __builtin_amdgcn_mfma_f32_16x16x32_bf16(A[ks], B[ks][j], acc[j], 0, 0, 0);
    #pragma unroll
    for (int j = 0; j < 4; ++j) {
      float s = 0.f, q = 0.f;
      #pragma unroll
      for (int rg = 0; rg < 4; ++rg) { float v = acc[j][rg]; s += v; q += v * v; }
      rs[j] += s; rq[j] += q;
    }
  }
  // reduce across the 4 kg groups (same columns, different rows)
  #pragma unroll
  for (int j = 0; j < 4; ++j) {
    rs[j] += __shfl_xor(rs[j], 16); rs[j] += __shfl_xor(rs[j], 32);
    rq[j] += __shfl_xor(rq[j], 16); rq[j] += __shfl_xor(rq[j], 32);
  }
  if (lane < 16) {
    #pragma unroll
    for (int j = 0; j < 4; ++j) {
      atomicAdd(&gsum[4 * lane + j], rs[j]);
      atomicAdd(&gsq[4 * lane + j], rq[j]);
    }
  }
}

__global__ void k_finalize(const float* __restrict__ gsum, const float* __restrict__ gsq,
                           const float* __restrict__ g, const float* __restrict__ be,
                           float* __restrict__ scale, float* __restrict__ shift, float denom) {
  int t = threadIdx.x;
  if (t < 64) {
    float m = gsum[t] / denom;
    float var = gsq[t] / denom - m * m;
    float is = rsqrtf(var + BN_EPS);
    float sc = g[t] * is;
    scale[t] = sc;
    shift[t] = be[t] - m * sc;
  }
}

__global__ __launch_bounds__(256) void k_edge_main(
    const float* __restrict__ attr, const int* __restrict__ ei_row,
    const int* __restrict__ ei_col, const float* __restrict__ x,
    const float* __restrict__ w1, const float* __restrict__ scaleE,
    const float* __restrict__ shiftE,
    __half* __restrict__ rsum, float* __restrict__ cnt, int E, int numTiles) {
  const int tid = threadIdx.x;
  const int wv = tid >> 6, lane = tid & 63;
  const int l15 = lane & 15, kg = lane >> 4;
  bf16x8 B[3][4];
  load_B96(B, w1, l15, kg);
  const f32x4 scv = *(const f32x4*)(scaleE + 4 * l15);
  const f32x4 shv = *(const f32x4*)(shiftE + 4 * l15);

  const f32x4 z = {0.f, 0.f, 0.f, 0.f};
  const int wstride = gridDim.x * 4;

  for (int t = blockIdx.x * 4 + wv; t < numTiles; t += wstride) {
    long e0 = (long)t * 16;
    bf16x8 A[3];
    edge_A(A, attr, ei_row, x, e0, E, l15, kg);

    int carr[4];
    #pragma unroll
    for (int rg = 0; rg < 4; ++rg) {
      long e = e0 + kg * 4 + rg;
      carr[rg] = (e < E) ? ei_col[e] : -1;
    }

    f32x4 acc[4]; acc[0] = z; acc[1] = z; acc[2] = z; acc[3] = z;
    #pragma unroll
    for (int ks = 0; ks < 3; ++ks)
      #pragma unroll
      for (int j = 0; j < 4; ++j)
        acc[j] = __builtin_amdgcn_mfma_f32_16x16x32_bf16(A[ks], B[ks][j], acc[j], 0, 0, 0);

    if (l15 == 0) {
      #pragma unroll
      for (int rg = 0; rg < 4; ++rg)
        if (carr[rg] >= 0) atomicAdd(&cnt[carr[rg]], 1.f);
    }

    #pragma unroll
    for (int rg = 0; rg < 4; ++rg) {
      int nd = carr[rg];
      if (nd < 0) continue;
      float v0 = fmaxf(acc[0][rg] * scv[0] + shv[0], 0.f);
      float v1 = fmaxf(acc[1][rg] * scv[1] + shv[1], 0.f);
      float v2 = fmaxf(acc[2][rg] * scv[2] + shv[2], 0.f);
      float v3 = fmaxf(acc[3][rg] * scv[3] + shv[3], 0.f);
      __half2 h01 = __halves2half2(__float2half(v0), __float2half(v1));
      __half2 h23 = __halves2half2(__float2half(v2), __float2half(v3));
      __half2* dst = (__half2*)(rsum + (size_t)nd * HID + 4 * l15);
      unsafeAtomicAdd(dst, h01);
      unsafeAtomicAdd(dst + 1, h23);
    }
  }
}

static __device__ __forceinline__ void unpack_h8(bf16x8& a, const __half* __restrict__ p, float ic) {
  union { int4 i4; __half2 h[4]; } u;
  u.i4 = *(const int4*)p;
  #pragma unroll
  for (int t = 0; t < 4; ++t) {
    float2 f = __half22float2(u.h[t]);
    a[2 * t]     = f2bf(f.x * ic);
    a[2 * t + 1] = f2bf(f.y * ic);
  }
}

// agg[n] = cnt>0 ? (rsum[n]/cnt)@W2 + b2 : 0   (stored bf16)
__global__ __launch_bounds__(256) void k_node_agg(
    const __half* __restrict__ rsum, const float* __restrict__ cnt,
    const float* __restrict__ w2, const float* __restrict__ b2,
    short* __restrict__ aggb, int N, int numTiles) {
  const int tid = threadIdx.x;
  const int wv = tid >> 6, lane = tid & 63;
  const int l15 = lane & 15, kg = lane >> 4;
  bf16x8 B[2][4];
  load_B64(B, w2, l15, kg);
  const f32x4 b2v = *(const f32x4*)(b2 + 4 * l15);

  const f32x4 z = {0.f, 0.f, 0.f, 0.f};
  const int wstride = gridDim.x * 4;

  for (int t = blockIdx.x * 4 + wv; t < numTiles; t += wstride) {
    long n0 = (long)t * 16;
    long n = n0 + l15;
    bf16x8 a0 = Z8, a1 = Z8;
    if (n < N) {
      float ic = 1.f / fmaxf(cnt[n], 1.f);
      const __half* rr = rsum + (size_t)n * HID;
      unpack_h8(a0, rr + kg * 8, ic);
      unpack_h8(a1, rr + 32 + kg * 8, ic);
    }
    f32x4 acc[4]; acc[0] = z; acc[1] = z; acc[2] = z; acc[3] = z;
    #pragma unroll
    for (int j = 0; j < 4; ++j) {
      acc[j] = __builtin_amdgcn_mfma_f32_16x16x32_bf16(a0, B[0][j], acc[j], 0, 0, 0);
      acc[j] = __builtin_amdgcn_mfma_f32_16x16x32_bf16(a1, B[1][j], acc[j], 0, 0, 0);
    }
    long no = n0 + kg * 4;
    #pragma unroll
    for (int rg = 0; rg < 4; ++rg) {
      long nr = no + rg;
      if (nr >= N) continue;
      bool has = (cnt[nr] > 0.f);
      bf16x4 o;
      #pragma unroll
      for (int j = 0; j < 4; ++j) {
        float v = has ? (acc[j][rg] + b2v[j]) : 0.f;
        o[j] = f2bf(v);
      }
      *(bf16x4*)(aggb + (size_t)nr * HID + 4 * l15) = o;
    }
  }
}

__global__ __launch_bounds__(256) void k_node_stats(
    const short* __restrict__ aggb, const float* __restrict__ x,
    const float* __restrict__ w3,
    float* __restrict__ gsum, float* __restrict__ gsq, int N, int numTiles) {
  const int tid = threadIdx.x;
  const int wv = tid >> 6, lane = tid & 63;
  const int l15 = lane & 15, kg = lane >> 4;
  bf16x8 B[3][4];
  load_B96(B, w3, l15, kg);

  float rs[4] = {0.f, 0.f, 0.f, 0.f};
  float rq[4] = {0.f, 0.f, 0.f, 0.f};
  const f32x4 z = {0.f, 0.f, 0.f, 0.f};
  const int wstride = gridDim.x * 4;

  for (int t = blockIdx.x * 4 + wv; t < numTiles; t += wstride) {
    bf16x8 A[3];
    node_A(A, aggb, x, (long)t * 16, N, l15, kg);
    f32x4 acc[4]; acc[0] = z; acc[1] = z; acc[2] = z; acc[3] = z;
    #pragma unroll
    for (int ks = 0; ks < 3; ++ks)
      #pragma unroll
      for (int j = 0; j < 4; ++j)
        acc[j] = __builtin_amdgcn_mfma_f32_16x16x32_bf16(A[ks], B[ks][j], acc[j], 0, 0, 0);
    #pragma unroll
    for (int j = 0; j < 4; ++j) {
      float s = 0.f, q = 0.f;
      #pragma unroll
      for (int rg = 0; rg < 4; ++rg) { float v = acc[j][rg]; s += v; q += v * v; }
      rs[j] += s; rq[j] += q;
    }
  }
  #pragma unroll
  for (int j = 0; j < 4; ++j) {
    rs[j] += __shfl_xor(rs[j], 16); rs[j] += __shfl_xor(rs[j], 32);
    rq[j] += __shfl_xor(rq[j], 16); rq[j] += __shfl_xor(rq[j], 32);
  }
  if (lane < 16) {
    #pragma unroll
    for (int j = 0; j < 4; ++j) {
      atomicAdd(&gsum[4 * lane + j], rs[j]);
      atomicAdd(&gsq[4 * lane + j], rq[j]);
    }
  }
}

// One wave per block: per-wave LDS roundtrip for the GEMM4 re-fragmentation,
// __syncthreads() (single-wave) provides the ds_write -> ds_read ordering.
__global__ __launch_bounds__(64) void k_node_main(
    const short* __restrict__ aggb, const float* __restrict__ x,
    const float* __restrict__ w3, const float* __restrict__ w4,
    const float* __restrict__ b4, const float* __restrict__ scaleN,
    const float* __restrict__ shiftN, float* __restrict__ out, int N, int numTiles) {
  __shared__ short R[16][RPAD];
  const int lane = threadIdx.x & 63;
  const int l15 = lane & 15, kg = lane >> 4;
  bf16x8 B3[3][4];
  load_B96(B3, w3, l15, kg);
  bf16x8 B4[2][4];
  load_B64(B4, w4, l15, kg);
  const f32x4 scv = *(const f32x4*)(scaleN + 4 * l15);
  const f32x4 shv = *(const f32x4*)(shiftN + 4 * l15);
  const f32x4 b4v = *(const f32x4*)(b4 + 4 * l15);

  const f32x4 z = {0.f, 0.f, 0.f, 0.f};

  for (int t = blockIdx.x; t < numTiles; t += gridDim.x) {
    long n0 = (long)t * 16;
    bf16x8 A[3];
    node_A(A, aggb, x, n0, N, l15, kg);

    f32x4 acc1[4]; acc1[0] = z; acc1[1] = z; acc1[2] = z; acc1[3] = z;
    #pragma unroll
    for (int ks = 0; ks < 3; ++ks)
      #pragma unroll
      for (int j = 0; j < 4; ++j)
        acc1[j] = __builtin_amdgcn_mfma_f32_16x16x32_bf16(A[ks], B3[ks][j], acc1[j], 0, 0, 0);

    __syncthreads();  // previous iteration's R reads complete
    #pragma unroll
    for (int rg = 0; rg < 4; ++rg) {
      bf16x4 o;
      #pragma unroll
      for (int j = 0; j < 4; ++j) {
        float v = fmaxf(acc1[j][rg] * scv[j] + shv[j], 0.f);
        o[j] = f2bf(v);
      }
      *(bf16x4*)&R[kg * 4 + rg][4 * l15] = o;
    }
    __syncthreads();

    f32x4 acc2[4]; acc2[0] = z; acc2[1] = z; acc2[2] = z; acc2[3] = z;
    #pragma unroll
    for (int ks = 0; ks < 2; ++ks) {
      bf16x8 a = *(const bf16x8*)&R[l15][ks * 32 + kg * 8];
      #pragma unroll
      for (int j = 0; j < 4; ++j)
        acc2[j] = __builtin_amdgcn_mfma_f32_16x16x32_bf16(a, B4[ks][j], acc2[j], 0, 0, 0);
    }

    long no = n0 + kg * 4;
    #pragma unroll
    for (int rg = 0; rg < 4; ++rg) {
      long nr = no + rg;
      if (nr >= N) continue;
      f32x4 o;
      #pragma unroll
      for (int j = 0; j < 4; ++j) o[j] = acc2[j][rg] + b4v[j];
      *(f32x4*)(out + (size_t)nr * HID + 4 * l15) = o;
    }
  }
}

extern "C" void kernel_launch(void* const* d_in, const int* in_sizes, int n_in,
                              void* d_out, int out_size, void* d_ws, size_t ws_size,
                              hipStream_t stream) {
  const float* x    = (const float*)d_in[0];
  const int*   ei   = (const int*)d_in[1];   // [2, E]: row = ei[0:E), col = ei[E:2E)
  const float* attr = (const float*)d_in[2];
  const float* w1   = (const float*)d_in[5];
  const float* g1   = (const float*)d_in[7];
  const float* be1  = (const float*)d_in[8];
  const float* w2   = (const float*)d_in[9];
  const float* b2   = (const float*)d_in[10];
  const float* w3   = (const float*)d_in[11];
  const float* g3   = (const float*)d_in[13];
  const float* be3  = (const float*)d_in[14];
  const float* w4   = (const float*)d_in[15];
  const float* b4   = (const float*)d_in[16];
  float* out = (float*)d_out;

  const int N = in_sizes[0] / 3;
  const int E = in_sizes[1] / 2;

  float* wsf = (float*)d_ws;
  float* gsumE  = wsf + 0;
  float* gsqE   = wsf + 64;
  float* scaleE = wsf + 128;
  float* shiftE = wsf + 192;
  float* gsumN  = wsf + 256;
  float* gsqN   = wsf + 320;
  float* scaleN = wsf + 384;
  float* shiftN = wsf + 448;
  __half* rsum  = (__half*)(wsf + 512);                 // N*64 f16  (= N*32 floats)
  float*  cnt   = wsf + 512 + (size_t)N * 32;           // N f32
  short*  aggb  = (short*)(wsf + 512 + (size_t)N * 33); // N*64 bf16 (= N*32 floats)

  // zero header + rsum + cnt (agg fully overwritten by k_node_agg)
  hipMemsetAsync(d_ws, 0, (512 + (size_t)N * 33) * sizeof(float), stream);

  const int tilesE = (E + 15) / 16;
  const int tilesN = (N + 15) / 16;
  const int gridE = 2048;
  const int gridN = 1024;
  const int gridM = tilesN < 4096 ? tilesN : 4096;

  k_edge_stats<<<gridE, 256, 0, stream>>>(attr, ei, x, w1, gsumE, gsqE, E, tilesE);
  k_finalize<<<1, 64, 0, stream>>>(gsumE, gsqE, g1, be1, scaleE, shiftE, (float)E);
  k_edge_main<<<gridE, 256, 0, stream>>>(attr, ei, ei + E, x, w1, scaleE, shiftE,
                                         rsum, cnt, E, tilesE);
  k_node_agg<<<gridN, 256, 0, stream>>>(rsum, cnt, w2, b2, aggb, N, tilesN);
  k_node_stats<<<gridN, 256, 0, stream>>>(aggb, x, w3, gsumN, gsqN, N, tilesN);
  k_finalize<<<1, 64, 0, stream>>>(gsumN, gsqN, g3, be3, scaleN, shiftN, (float)N);
  k_node_main<<<gridM, 64, 0, stream>>>(aggb, x, w3, w4, b4, scaleN, shiftN, out, N, tilesN);
}